// Round 4
// baseline (1025.869 us; speedup 1.0000x reference)
//
#include <hip/hip_runtime.h>
#include <hip/hip_bf16.h>

// Problem constants: B=2, S=2048, H=896, I=4864, E=4, K=2
#define E_ 4
#define H_ 896
#define I_ 4864
#define T_ 4096          // B*S tokens
#define P_ 8192          // T_*K pairs
#define KS2 2432         // I_/2, split-K half for gemm2 (38 * 64)
#define WBLK 17024       // WN/1024 blocks per weight tensor in cast3

typedef unsigned short u16;
typedef __attribute__((ext_vector_type(8))) short short8;   // 8 x bf16 bits (4 VGPRs)
typedef __attribute__((ext_vector_type(4))) float f32x4;

__device__ __forceinline__ void gload16(const void* g, void* l) {
  __builtin_amdgcn_global_load_lds(
      (const __attribute__((address_space(1))) unsigned int*)g,
      (__attribute__((address_space(3))) unsigned int*)l, 16, 0, 0);
}

__device__ __forceinline__ u16 f2bf(float f) {
  unsigned int u = __builtin_bit_cast(unsigned int, f);
  unsigned int r = (u + 0x7FFFu + ((u >> 16) & 1u)) >> 16;   // RNE
  return (u16)r;
}

// ---------------- cast 3 weight tensors fp32 -> bf16 in one launch ----------------
__global__ __launch_bounds__(256) void cast3_kernel(const float* __restrict__ a,
                                                    const float* __restrict__ b,
                                                    const float* __restrict__ c,
                                                    u16* __restrict__ oa,
                                                    u16* __restrict__ ob,
                                                    u16* __restrict__ oc) {
  int wsel = blockIdx.x / WBLK;                       // 0,1,2
  long base = ((long)(blockIdx.x % WBLK) * 256 + threadIdx.x) * 4;
  const float* in = (wsel == 0) ? a : (wsel == 1) ? b : c;
  u16* out = (wsel == 0) ? oa : (wsel == 1) ? ob : oc;
  float4 v = *reinterpret_cast<const float4*>(in + base);   // WN % 1024 == 0, no tail
  ushort4 o;
  o.x = f2bf(v.x); o.y = f2bf(v.y); o.z = f2bf(v.z); o.w = f2bf(v.w);
  *reinterpret_cast<ushort4*>(out + base) = o;
}

// ---------------- router: fp32 logits, top-2, renorm weights; also casts x->bf16 ----
__global__ __launch_bounds__(64) void router_kernel(const float* __restrict__ x,
                                                    const float* __restrict__ rw,
                                                    int* __restrict__ cnt,
                                                    int* __restrict__ pairs,
                                                    float* __restrict__ wgt,
                                                    u16* __restrict__ xb) {
  int t = blockIdx.x;
  int lane = threadIdx.x;
  const float* xr = x + (long)t * H_;
  float a0 = 0.f, a1 = 0.f, a2 = 0.f, a3 = 0.f;
  for (int h = lane; h < H_; h += 64) {
    float xv = xr[h];
    a0 += xv * rw[0 * H_ + h];
    a1 += xv * rw[1 * H_ + h];
    a2 += xv * rw[2 * H_ + h];
    a3 += xv * rw[3 * H_ + h];
    xb[(long)t * H_ + h] = f2bf(xv);                  // fused x cast (re-read hits L1)
  }
  for (int off = 32; off > 0; off >>= 1) {
    a0 += __shfl_xor(a0, off, 64);
    a1 += __shfl_xor(a1, off, 64);
    a2 += __shfl_xor(a2, off, 64);
    a3 += __shfl_xor(a3, off, 64);
  }
  if (lane == 0) {
    float l[4] = {a0, a1, a2, a3};
    int i0 = 0;
    for (int e = 1; e < 4; ++e) if (l[e] > l[i0]) i0 = e;         // first max (tie -> lower idx)
    int i1 = -1;
    for (int e = 0; e < 4; ++e) {
      if (e == i0) continue;
      if (i1 < 0 || l[e] > l[i1]) i1 = e;
    }
    float w0 = 1.0f / (1.0f + __expf(l[i1] - l[i0]));
    int j0 = atomicAdd(&cnt[i0], 1);
    pairs[i0 * T_ + j0] = 2 * t;
    wgt[2 * t] = w0;
    int j1 = atomicAdd(&cnt[i1], 1);
    pairs[i1 * T_ + j1] = 2 * t + 1;
    wgt[2 * t + 1] = 1.0f - w0;
  }
}

// LDS layout (both GEMMs): 128 rows x 64 cols bf16, 8 chunks of 8 elems/row.
// Physical chunk p of row r holds LOGICAL chunk p ^ (r&7) (XOR folded into the
// staging GLOBAL address so global_load_lds keeps its wave-uniform LDS mapping).
// Bank-conflict-free (verified: SQ_LDS_BANK_CONFLICT == 0).
//
// Grid orientation (both GEMMs): blockIdx.x = N-col (fastest-varying).  R3's
// bx=M layout cut FETCH 422->295MB but collapsed achieved BW 2.8->1.2 TB/s
// (resident blocks shared too few B streams -> latency-bound).  Keep N-fastest.

// ---------------- GEMM1: h = silu(x @ gw^T) * (x @ uw^T), gathered rows ----------------
// grid: (I/128 [N], T/128 [M], E). 128x128 tile, BK=64, 4 waves each 64x64.
// LDS 48.5KB -> 3 blocks/CU; launch_bounds(256,3) to actually get 3 resident.
__global__ __launch_bounds__(256, 3) void gemm1_kernel(const u16* __restrict__ xb,
                                                       const u16* __restrict__ gw,
                                                       const u16* __restrict__ uw,
                                                       const int* __restrict__ cnt,
                                                       const int* __restrict__ pairs,
                                                       u16* __restrict__ hbuf) {
  int e = blockIdx.z;
  int n = cnt[e];
  int row0 = blockIdx.y * 128;
  if (row0 >= n) return;
  int col0 = blockIdx.x * 128;

  __shared__ alignas(16) u16 As[128 * 64];
  __shared__ alignas(16) u16 Bg[128 * 64];
  __shared__ alignas(16) u16 Bu[128 * 64];
  __shared__ int rows[128];

  int tid = threadIdx.x;
  if (tid < 128) {
    int j = row0 + tid;
    if (j >= n) j = n - 1;           // clamp; epilogue guards duplicate writes
    rows[tid] = pairs[e * T_ + j];
  }
  __syncthreads();

  int rr = tid >> 3;                 // 0..31: row within 32-row staging round
  int cc = tid & 7;                  // physical 16B chunk within row
  long eoff = (long)e * I_ * H_;

  const u16* aP[4]; const u16* gP[4]; const u16* uP[4];
  u16* lA[4]; u16* lG[4]; u16* lU[4];
#pragma unroll
  for (int q = 0; q < 4; ++q) {
    int gr = rr + 32 * q;
    int g8 = (cc ^ (gr & 7)) * 8;    // swizzled logical chunk -> global offset
    aP[q] = xb + (long)(rows[gr] >> 1) * H_ + g8;
    gP[q] = gw + eoff + (long)(col0 + gr) * H_ + g8;
    uP[q] = uw + eoff + (long)(col0 + gr) * H_ + g8;
    lA[q] = As + q * 2048 + tid * 8;
    lG[q] = Bg + q * 2048 + tid * 8;
    lU[q] = Bu + q * 2048 + tid * 8;
  }

  f32x4 accg[4][4] = {};
  f32x4 accu[4][4] = {};

  int lane = tid & 63;
  int wave = tid >> 6;
  int wm = (wave >> 1) * 64;
  int wn = (wave & 1) * 64;
  int lm = lane & 15;
  int qv = lane >> 4;                // which logical k-chunk within a 32-k half
  int px = qv ^ (lm & 7);            // physical chunk for kh=0

  for (int kt = 0; kt < H_; kt += 64) {
    __syncthreads();
#pragma unroll
    for (int q = 0; q < 4; ++q) {
      gload16(aP[q] + kt, lA[q]);
      gload16(gP[q] + kt, lG[q]);
      gload16(uP[q] + kt, lU[q]);
    }
    __syncthreads();

#pragma unroll
    for (int kh = 0; kh < 2; ++kh) {
      int po = (px ^ (kh << 2)) * 8;
      short8 af[4];
#pragma unroll
      for (int bi = 0; bi < 4; ++bi)
        af[bi] = *reinterpret_cast<const short8*>(&As[(wm + bi * 16 + lm) * 64 + po]);
#pragma unroll
      for (int bj = 0; bj < 4; ++bj) {
        short8 bgf = *reinterpret_cast<const short8*>(&Bg[(wn + bj * 16 + lm) * 64 + po]);
        short8 buf = *reinterpret_cast<const short8*>(&Bu[(wn + bj * 16 + lm) * 64 + po]);
#pragma unroll
        for (int bi = 0; bi < 4; ++bi) {
          accg[bi][bj] = __builtin_amdgcn_mfma_f32_16x16x32_bf16(af[bi], bgf, accg[bi][bj], 0, 0, 0);
          accu[bi][bj] = __builtin_amdgcn_mfma_f32_16x16x32_bf16(af[bi], buf, accu[bi][bj], 0, 0, 0);
        }
      }
    }
  }

  // epilogue: C/D layout col=lane&15, row=(lane>>4)*4+reg  [m89-verified]
  int rq = (lane >> 4) * 4;
#pragma unroll
  for (int bi = 0; bi < 4; ++bi) {
#pragma unroll
    for (int r = 0; r < 4; ++r) {
      int rloc = wm + bi * 16 + rq + r;
      if (row0 + rloc < n) {
        long p = rows[rloc];
        u16* hr = hbuf + p * (long)I_ + col0 + wn + lm;
#pragma unroll
        for (int bj = 0; bj < 4; ++bj) {
          float g = accg[bi][bj][r];
          float u = accu[bi][bj][r];
          float s = g / (1.0f + __expf(-g));   // silu
          hr[bj * 16] = f2bf(s * u);
        }
      }
    }
  }
}

// ---------------- GEMM2: ybuf[split][p] = h[p] @ dw[e]^T (raw, unweighted) --------
// grid: (H/128 [N]=7, T/128 [M], E*2 [e,split]).  Split-K partials to separate
// ybuf halves; combine applies routing weights (no atomics, no d_out zeroing).
// LDS 32.5KB -> 4 blocks/CU.
__global__ __launch_bounds__(256, 4) void gemm2_kernel(const u16* __restrict__ hbuf,
                                                       const u16* __restrict__ dw,
                                                       const int* __restrict__ cnt,
                                                       const int* __restrict__ pairs,
                                                       float* __restrict__ ybuf) {
  int bz = blockIdx.z;
  int e = bz >> 1;
  int sp = bz & 1;
  int k0 = sp * KS2;
  int n = cnt[e];
  int row0 = blockIdx.y * 128;
  if (row0 >= n) return;
  int col0 = blockIdx.x * 128;

  __shared__ alignas(16) u16 As[128 * 64];
  __shared__ alignas(16) u16 Bs[128 * 64];
  __shared__ int rows[128];

  int tid = threadIdx.x;
  if (tid < 128) {
    int j = row0 + tid;
    if (j >= n) j = n - 1;
    rows[tid] = pairs[e * T_ + j];
  }
  __syncthreads();

  int rr = tid >> 3;
  int cc = tid & 7;

  const u16* aP[4]; const u16* bP[4];
  u16* lA[4]; u16* lB[4];
#pragma unroll
  for (int q = 0; q < 4; ++q) {
    int gr = rr + 32 * q;
    int g8 = (cc ^ (gr & 7)) * 8;
    aP[q] = hbuf + (long)rows[gr] * I_ + k0 + g8;
    bP[q] = dw + (long)e * H_ * I_ + (long)(col0 + gr) * I_ + k0 + g8;
    lA[q] = As + q * 2048 + tid * 8;
    lB[q] = Bs + q * 2048 + tid * 8;
  }

  f32x4 acc[4][4] = {};

  int lane = tid & 63;
  int wave = tid >> 6;
  int wm = (wave >> 1) * 64;
  int wn = (wave & 1) * 64;
  int lm = lane & 15;
  int qv = lane >> 4;
  int px = qv ^ (lm & 7);

  for (int kt = 0; kt < KS2; kt += 64) {
    __syncthreads();
#pragma unroll
    for (int q = 0; q < 4; ++q) {
      gload16(aP[q] + kt, lA[q]);
      gload16(bP[q] + kt, lB[q]);
    }
    __syncthreads();

#pragma unroll
    for (int kh = 0; kh < 2; ++kh) {
      int po = (px ^ (kh << 2)) * 8;
      short8 af[4];
#pragma unroll
      for (int bi = 0; bi < 4; ++bi)
        af[bi] = *reinterpret_cast<const short8*>(&As[(wm + bi * 16 + lm) * 64 + po]);
#pragma unroll
      for (int bj = 0; bj < 4; ++bj) {
        short8 bf = *reinterpret_cast<const short8*>(&Bs[(wn + bj * 16 + lm) * 64 + po]);
#pragma unroll
        for (int bi = 0; bi < 4; ++bi)
          acc[bi][bj] = __builtin_amdgcn_mfma_f32_16x16x32_bf16(af[bi], bf, acc[bi][bj], 0, 0, 0);
      }
    }
  }

  int rq = (lane >> 4) * 4;
#pragma unroll
  for (int bi = 0; bi < 4; ++bi) {
#pragma unroll
    for (int r = 0; r < 4; ++r) {
      int rloc = wm + bi * 16 + rq + r;
      if (row0 + rloc < n) {
        int p = rows[rloc];
        float* orow = ybuf + ((long)sp * P_ + p) * H_ + col0 + wn + lm;
#pragma unroll
        for (int bj = 0; bj < 4; ++bj)
          orow[bj * 16] = acc[bi][bj][r];
      }
    }
  }
}

// ---------------- combine: out[t] = w0*(y00+y01) + w1*(y10+y11) ----------------
__global__ __launch_bounds__(256) void combine_kernel(const float* __restrict__ Y,
                                                      const float* __restrict__ wgt,
                                                      float* __restrict__ out) {
  long gid = (long)blockIdx.x * 256 + threadIdx.x;    // over T_*224 float4 slots
  int t = (int)(gid / 224);
  int hc = (int)(gid % 224);
  float w0 = wgt[2 * t];
  float w1 = wgt[2 * t + 1];
  const float4* y00 = reinterpret_cast<const float4*>(Y + ((long)2 * t) * H_) + hc;
  const float4* y01 = reinterpret_cast<const float4*>(Y + ((long)P_ + 2 * t) * H_) + hc;
  const float4* y10 = reinterpret_cast<const float4*>(Y + ((long)2 * t + 1) * H_) + hc;
  const float4* y11 = reinterpret_cast<const float4*>(Y + ((long)P_ + 2 * t + 1) * H_) + hc;
  float4 a = *y00, b = *y01, c = *y10, d = *y11;
  float4 o;
  o.x = w0 * (a.x + b.x) + w1 * (c.x + d.x);
  o.y = w0 * (a.y + b.y) + w1 * (c.y + d.y);
  o.z = w0 * (a.z + b.z) + w1 * (c.z + d.z);
  o.w = w0 * (a.w + b.w) + w1 * (c.w + d.w);
  *(reinterpret_cast<float4*>(out + (long)t * H_) + hc) = o;
}

extern "C" void kernel_launch(void* const* d_in, const int* in_sizes, int n_in,
                              void* d_out, int out_size, void* d_ws, size_t ws_size,
                              hipStream_t stream) {
  const float* x        = (const float*)d_in[0];
  const float* router_w = (const float*)d_in[1];
  const float* gate_w   = (const float*)d_in[2];
  const float* up_w     = (const float*)d_in[3];
  const float* down_w   = (const float*)d_in[4];
  float* out = (float*)d_out;

  const long WN = (long)E_ * I_ * H_;   // 17,432,576 elements per weight tensor

  char* ws = (char*)d_ws;
  size_t off = 0;
  auto alloc = [&](size_t bytes) {
    void* p = ws + off;
    off = (off + bytes + 255) & ~(size_t)255;
    return p;
  };
  u16* gw_b  = (u16*)alloc(WN * 2);
  u16* uw_b  = (u16*)alloc(WN * 2);
  u16* dw_b  = (u16*)alloc(WN * 2);
  u16* xb    = (u16*)alloc((long)T_ * H_ * 2);
  u16* hbuf  = (u16*)alloc((long)P_ * I_ * 2);
  int* cnt   = (int*)alloc(256);
  int* pairs = (int*)alloc((long)E_ * T_ * 4);
  float* wgt = (float*)alloc((long)P_ * 4);
  // ybuf (2*P_*H_ fp32 = 58.7 MB) ALIASES gw_b/uw_b (69.7 MB): gemm1 has
  // finished with gate/up weights before gemm2 writes ybuf (serial stream).
  float* ybuf = (float*)gw_b;

  hipMemsetAsync(cnt, 0, 256, stream);

  cast3_kernel<<<3 * WBLK, 256, 0, stream>>>(gate_w, up_w, down_w, gw_b, uw_b, dw_b);

  router_kernel<<<T_, 64, 0, stream>>>(x, router_w, cnt, pairs, wgt, xb);

  dim3 g1(I_ / 128, T_ / 128, E_);            // (38, 32, 4): N fastest
  gemm1_kernel<<<g1, 256, 0, stream>>>(xb, gw_b, uw_b, cnt, pairs, hbuf);

  dim3 g2(H_ / 128, T_ / 128, E_ * 2);        // (7, 32, 8): N fastest
  gemm2_kernel<<<g2, 256, 0, stream>>>(hbuf, dw_b, cnt, pairs, ybuf);

  combine_kernel<<<(T_ * 224) / 256, 256, 0, stream>>>(ybuf, wgt, out);
}

// Round 5
// 651.897 us; speedup vs baseline: 1.5737x; 1.5737x over previous
//
#include <hip/hip_runtime.h>
#include <hip/hip_bf16.h>

// Problem constants: B=2, S=2048, H=896, I=4864, E=4, K=2
#define E_ 4
#define H_ 896
#define I_ 4864
#define T_ 4096          // B*S tokens
#define P_ 8192          // T_*K pairs
#define KS2 2432         // I_/2, split-K half for gemm2 (38 * 64)
#define WBLK 17024       // WN/1024 blocks per weight tensor in cast3

typedef unsigned short u16;
typedef __attribute__((ext_vector_type(8))) short short8;   // 8 x bf16 bits (4 VGPRs)
typedef __attribute__((ext_vector_type(4))) float f32x4;

__device__ __forceinline__ void gload16(const void* g, void* l) {
  __builtin_amdgcn_global_load_lds(
      (const __attribute__((address_space(1))) unsigned int*)g,
      (__attribute__((address_space(3))) unsigned int*)l, 16, 0, 0);
}

__device__ __forceinline__ u16 f2bf(float f) {
  unsigned int u = __builtin_bit_cast(unsigned int, f);
  unsigned int r = (u + 0x7FFFu + ((u >> 16) & 1u)) >> 16;   // RNE
  return (u16)r;
}

// ---------------- cast 3 weight tensors fp32 -> bf16 in one launch ----------------
__global__ __launch_bounds__(256) void cast3_kernel(const float* __restrict__ a,
                                                    const float* __restrict__ b,
                                                    const float* __restrict__ c,
                                                    u16* __restrict__ oa,
                                                    u16* __restrict__ ob,
                                                    u16* __restrict__ oc) {
  int wsel = blockIdx.x / WBLK;                       // 0,1,2
  long base = ((long)(blockIdx.x % WBLK) * 256 + threadIdx.x) * 4;
  const float* in = (wsel == 0) ? a : (wsel == 1) ? b : c;
  u16* out = (wsel == 0) ? oa : (wsel == 1) ? ob : oc;
  float4 v = *reinterpret_cast<const float4*>(in + base);   // WN % 1024 == 0, no tail
  ushort4 o;
  o.x = f2bf(v.x); o.y = f2bf(v.y); o.z = f2bf(v.z); o.w = f2bf(v.w);
  *reinterpret_cast<ushort4*>(out + base) = o;
}

// ---------------- router: fp32 logits, top-2, renorm weights; also casts x->bf16 ----
__global__ __launch_bounds__(64) void router_kernel(const float* __restrict__ x,
                                                    const float* __restrict__ rw,
                                                    int* __restrict__ cnt,
                                                    int* __restrict__ pairs,
                                                    float* __restrict__ wgt,
                                                    u16* __restrict__ xb) {
  int t = blockIdx.x;
  int lane = threadIdx.x;
  const float* xr = x + (long)t * H_;
  float a0 = 0.f, a1 = 0.f, a2 = 0.f, a3 = 0.f;
  for (int h = lane; h < H_; h += 64) {
    float xv = xr[h];
    a0 += xv * rw[0 * H_ + h];
    a1 += xv * rw[1 * H_ + h];
    a2 += xv * rw[2 * H_ + h];
    a3 += xv * rw[3 * H_ + h];
    xb[(long)t * H_ + h] = f2bf(xv);                  // fused x cast (re-read hits L1)
  }
  for (int off = 32; off > 0; off >>= 1) {
    a0 += __shfl_xor(a0, off, 64);
    a1 += __shfl_xor(a1, off, 64);
    a2 += __shfl_xor(a2, off, 64);
    a3 += __shfl_xor(a3, off, 64);
  }
  if (lane == 0) {
    float l[4] = {a0, a1, a2, a3};
    int i0 = 0;
    for (int e = 1; e < 4; ++e) if (l[e] > l[i0]) i0 = e;         // first max (tie -> lower idx)
    int i1 = -1;
    for (int e = 0; e < 4; ++e) {
      if (e == i0) continue;
      if (i1 < 0 || l[e] > l[i1]) i1 = e;
    }
    float w0 = 1.0f / (1.0f + __expf(l[i1] - l[i0]));
    int j0 = atomicAdd(&cnt[i0], 1);
    pairs[i0 * T_ + j0] = 2 * t;
    wgt[2 * t] = w0;
    int j1 = atomicAdd(&cnt[i1], 1);
    pairs[i1 * T_ + j1] = 2 * t + 1;
    wgt[2 * t + 1] = 1.0f - w0;
  }
}

// LDS layout (both GEMMs): 128 rows x 64 cols bf16, 8 chunks of 8 elems/row.
// Physical chunk p of row r holds LOGICAL chunk p ^ (r&7) (XOR folded into the
// staging GLOBAL address).  Bank-conflict-free (verified: SQ_LDS_BANK_CONFLICT==0).
//
// Grid: N fastest (bx).  R3's bx=M cut FETCH but collapsed BW 2.8->1.2 TB/s.
// Occupancy: gemm1 MUST stay at launch_bounds(256,2) — (256,3) caps the unified
// VGPR budget at 170/wave vs ~232 needed (128 acc + 104 arch) and spills
// accumulators to scratch (R4: WRITE_SIZE 78->579MB, dur 181->417us).

// ---------------- GEMM1: h = silu(x @ gw^T) * (x @ uw^T), gathered rows ----------------
// grid: (I/128 [N], T/128 [M], E). 128x128 tile, BK=64, 4 waves each 64x64.
__global__ __launch_bounds__(256, 2) void gemm1_kernel(const u16* __restrict__ xb,
                                                       const u16* __restrict__ gw,
                                                       const u16* __restrict__ uw,
                                                       const int* __restrict__ cnt,
                                                       const int* __restrict__ pairs,
                                                       u16* __restrict__ hbuf) {
  int e = blockIdx.z;
  int n = cnt[e];
  int row0 = blockIdx.y * 128;
  if (row0 >= n) return;
  int col0 = blockIdx.x * 128;

  __shared__ alignas(16) u16 As[128 * 64];
  __shared__ alignas(16) u16 Bg[128 * 64];
  __shared__ alignas(16) u16 Bu[128 * 64];
  __shared__ int rows[128];

  int tid = threadIdx.x;
  if (tid < 128) {
    int j = row0 + tid;
    if (j >= n) j = n - 1;           // clamp; epilogue guards duplicate writes
    rows[tid] = pairs[e * T_ + j];
  }
  __syncthreads();

  int rr = tid >> 3;                 // 0..31: row within 32-row staging round
  int cc = tid & 7;                  // physical 16B chunk within row
  long eoff = (long)e * I_ * H_;

  const u16* aP[4]; const u16* gP[4]; const u16* uP[4];
  u16* lA[4]; u16* lG[4]; u16* lU[4];
#pragma unroll
  for (int q = 0; q < 4; ++q) {
    int gr = rr + 32 * q;
    int g8 = (cc ^ (gr & 7)) * 8;    // swizzled logical chunk -> global offset
    aP[q] = xb + (long)(rows[gr] >> 1) * H_ + g8;
    gP[q] = gw + eoff + (long)(col0 + gr) * H_ + g8;
    uP[q] = uw + eoff + (long)(col0 + gr) * H_ + g8;
    lA[q] = As + q * 2048 + tid * 8;
    lG[q] = Bg + q * 2048 + tid * 8;
    lU[q] = Bu + q * 2048 + tid * 8;
  }

  f32x4 accg[4][4] = {};
  f32x4 accu[4][4] = {};

  int lane = tid & 63;
  int wave = tid >> 6;
  int wm = (wave >> 1) * 64;
  int wn = (wave & 1) * 64;
  int lm = lane & 15;
  int qv = lane >> 4;                // which logical k-chunk within a 32-k half
  int px = qv ^ (lm & 7);            // physical chunk for kh=0

  for (int kt = 0; kt < H_; kt += 64) {
    __syncthreads();
#pragma unroll
    for (int q = 0; q < 4; ++q) {
      gload16(aP[q] + kt, lA[q]);
      gload16(gP[q] + kt, lG[q]);
      gload16(uP[q] + kt, lU[q]);
    }
    __syncthreads();

#pragma unroll
    for (int kh = 0; kh < 2; ++kh) {
      int po = (px ^ (kh << 2)) * 8;
      short8 af[4];
#pragma unroll
      for (int bi = 0; bi < 4; ++bi)
        af[bi] = *reinterpret_cast<const short8*>(&As[(wm + bi * 16 + lm) * 64 + po]);
#pragma unroll
      for (int bj = 0; bj < 4; ++bj) {
        short8 bgf = *reinterpret_cast<const short8*>(&Bg[(wn + bj * 16 + lm) * 64 + po]);
        short8 buf = *reinterpret_cast<const short8*>(&Bu[(wn + bj * 16 + lm) * 64 + po]);
#pragma unroll
        for (int bi = 0; bi < 4; ++bi) {
          accg[bi][bj] = __builtin_amdgcn_mfma_f32_16x16x32_bf16(af[bi], bgf, accg[bi][bj], 0, 0, 0);
          accu[bi][bj] = __builtin_amdgcn_mfma_f32_16x16x32_bf16(af[bi], buf, accu[bi][bj], 0, 0, 0);
        }
      }
    }
  }

  // epilogue: C/D layout col=lane&15, row=(lane>>4)*4+reg  [m89-verified]
  int rq = (lane >> 4) * 4;
#pragma unroll
  for (int bi = 0; bi < 4; ++bi) {
#pragma unroll
    for (int r = 0; r < 4; ++r) {
      int rloc = wm + bi * 16 + rq + r;
      if (row0 + rloc < n) {
        long p = rows[rloc];
        u16* hr = hbuf + p * (long)I_ + col0 + wn + lm;
#pragma unroll
        for (int bj = 0; bj < 4; ++bj) {
          float g = accg[bi][bj][r];
          float u = accu[bi][bj][r];
          float s = g / (1.0f + __expf(-g));   // silu
          hr[bj * 16] = f2bf(s * u);
        }
      }
    }
  }
}

// ---------------- GEMM2: ybuf[split][p] = h[p] @ dw[e]^T (raw, unweighted) --------
// grid: (H/128 [N]=7, T/128 [M], E*2 [e,split]).  Split-K partials to separate
// ybuf halves; combine applies routing weights (no atomics, no d_out zeroing).
// (256,3): budget 170/wave vs ~124 needed (64 acc + 60 arch) — verified no spill.
__global__ __launch_bounds__(256, 3) void gemm2_kernel(const u16* __restrict__ hbuf,
                                                       const u16* __restrict__ dw,
                                                       const int* __restrict__ cnt,
                                                       const int* __restrict__ pairs,
                                                       float* __restrict__ ybuf) {
  int bz = blockIdx.z;
  int e = bz >> 1;
  int sp = bz & 1;
  int k0 = sp * KS2;
  int n = cnt[e];
  int row0 = blockIdx.y * 128;
  if (row0 >= n) return;
  int col0 = blockIdx.x * 128;

  __shared__ alignas(16) u16 As[128 * 64];
  __shared__ alignas(16) u16 Bs[128 * 64];
  __shared__ int rows[128];

  int tid = threadIdx.x;
  if (tid < 128) {
    int j = row0 + tid;
    if (j >= n) j = n - 1;
    rows[tid] = pairs[e * T_ + j];
  }
  __syncthreads();

  int rr = tid >> 3;
  int cc = tid & 7;

  const u16* aP[4]; const u16* bP[4];
  u16* lA[4]; u16* lB[4];
#pragma unroll
  for (int q = 0; q < 4; ++q) {
    int gr = rr + 32 * q;
    int g8 = (cc ^ (gr & 7)) * 8;
    aP[q] = hbuf + (long)rows[gr] * I_ + k0 + g8;
    bP[q] = dw + (long)e * H_ * I_ + (long)(col0 + gr) * I_ + k0 + g8;
    lA[q] = As + q * 2048 + tid * 8;
    lB[q] = Bs + q * 2048 + tid * 8;
  }

  f32x4 acc[4][4] = {};

  int lane = tid & 63;
  int wave = tid >> 6;
  int wm = (wave >> 1) * 64;
  int wn = (wave & 1) * 64;
  int lm = lane & 15;
  int qv = lane >> 4;
  int px = qv ^ (lm & 7);

  for (int kt = 0; kt < KS2; kt += 64) {
    __syncthreads();
#pragma unroll
    for (int q = 0; q < 4; ++q) {
      gload16(aP[q] + kt, lA[q]);
      gload16(bP[q] + kt, lB[q]);
    }
    __syncthreads();

#pragma unroll
    for (int kh = 0; kh < 2; ++kh) {
      int po = (px ^ (kh << 2)) * 8;
      short8 af[4];
#pragma unroll
      for (int bi = 0; bi < 4; ++bi)
        af[bi] = *reinterpret_cast<const short8*>(&As[(wm + bi * 16 + lm) * 64 + po]);
#pragma unroll
      for (int bj = 0; bj < 4; ++bj) {
        short8 bf = *reinterpret_cast<const short8*>(&Bs[(wn + bj * 16 + lm) * 64 + po]);
#pragma unroll
        for (int bi = 0; bi < 4; ++bi)
          acc[bi][bj] = __builtin_amdgcn_mfma_f32_16x16x32_bf16(af[bi], bf, acc[bi][bj], 0, 0, 0);
      }
    }
  }

  int rq = (lane >> 4) * 4;
#pragma unroll
  for (int bi = 0; bi < 4; ++bi) {
#pragma unroll
    for (int r = 0; r < 4; ++r) {
      int rloc = wm + bi * 16 + rq + r;
      if (row0 + rloc < n) {
        int p = rows[rloc];
        float* orow = ybuf + ((long)sp * P_ + p) * H_ + col0 + wn + lm;
#pragma unroll
        for (int bj = 0; bj < 4; ++bj)
          orow[bj * 16] = acc[bi][bj][r];
      }
    }
  }
}

// ---------------- combine: out[t] = w0*(y00+y01) + w1*(y10+y11) ----------------
__global__ __launch_bounds__(256) void combine_kernel(const float* __restrict__ Y,
                                                      const float* __restrict__ wgt,
                                                      float* __restrict__ out) {
  long gid = (long)blockIdx.x * 256 + threadIdx.x;    // over T_*224 float4 slots
  int t = (int)(gid / 224);
  int hc = (int)(gid % 224);
  float w0 = wgt[2 * t];
  float w1 = wgt[2 * t + 1];
  const float4* y00 = reinterpret_cast<const float4*>(Y + ((long)2 * t) * H_) + hc;
  const float4* y01 = reinterpret_cast<const float4*>(Y + ((long)P_ + 2 * t) * H_) + hc;
  const float4* y10 = reinterpret_cast<const float4*>(Y + ((long)2 * t + 1) * H_) + hc;
  const float4* y11 = reinterpret_cast<const float4*>(Y + ((long)P_ + 2 * t + 1) * H_) + hc;
  float4 a = *y00, b = *y01, c = *y10, d = *y11;
  float4 o;
  o.x = w0 * (a.x + b.x) + w1 * (c.x + d.x);
  o.y = w0 * (a.y + b.y) + w1 * (c.y + d.y);
  o.z = w0 * (a.z + b.z) + w1 * (c.z + d.z);
  o.w = w0 * (a.w + b.w) + w1 * (c.w + d.w);
  *(reinterpret_cast<float4*>(out + (long)t * H_) + hc) = o;
}

extern "C" void kernel_launch(void* const* d_in, const int* in_sizes, int n_in,
                              void* d_out, int out_size, void* d_ws, size_t ws_size,
                              hipStream_t stream) {
  const float* x        = (const float*)d_in[0];
  const float* router_w = (const float*)d_in[1];
  const float* gate_w   = (const float*)d_in[2];
  const float* up_w     = (const float*)d_in[3];
  const float* down_w   = (const float*)d_in[4];
  float* out = (float*)d_out;

  const long WN = (long)E_ * I_ * H_;   // 17,432,576 elements per weight tensor

  char* ws = (char*)d_ws;
  size_t off = 0;
  auto alloc = [&](size_t bytes) {
    void* p = ws + off;
    off = (off + bytes + 255) & ~(size_t)255;
    return p;
  };
  u16* gw_b  = (u16*)alloc(WN * 2);
  u16* uw_b  = (u16*)alloc(WN * 2);
  u16* dw_b  = (u16*)alloc(WN * 2);
  u16* xb    = (u16*)alloc((long)T_ * H_ * 2);
  u16* hbuf  = (u16*)alloc((long)P_ * I_ * 2);
  int* cnt   = (int*)alloc(256);
  int* pairs = (int*)alloc((long)E_ * T_ * 4);
  float* wgt = (float*)alloc((long)P_ * 4);
  // ybuf (2*P_*H_ fp32 = 58.7 MB) ALIASES gw_b/uw_b (69.7 MB): gemm1 has
  // finished with gate/up weights before gemm2 writes ybuf (serial stream).
  float* ybuf = (float*)gw_b;

  hipMemsetAsync(cnt, 0, 256, stream);

  cast3_kernel<<<3 * WBLK, 256, 0, stream>>>(gate_w, up_w, down_w, gw_b, uw_b, dw_b);

  router_kernel<<<T_, 64, 0, stream>>>(x, router_w, cnt, pairs, wgt, xb);

  dim3 g1(I_ / 128, T_ / 128, E_);            // (38, 32, 4): N fastest
  gemm1_kernel<<<g1, 256, 0, stream>>>(xb, gw_b, uw_b, cnt, pairs, hbuf);

  dim3 g2(H_ / 128, T_ / 128, E_ * 2);        // (7, 32, 8): N fastest
  gemm2_kernel<<<g2, 256, 0, stream>>>(hbuf, dw_b, cnt, pairs, ybuf);

  combine_kernel<<<(T_ * 224) / 256, 256, 0, stream>>>(ybuf, wgt, out);
}